// Round 3
// baseline (267.242 us; speedup 1.0000x reference)
//
#include <hip/hip_runtime.h>
#include <hip/hip_bf16.h>
#include <math.h>

typedef __bf16 bf16;
typedef __attribute__((ext_vector_type(8))) __bf16 bf16x8;
typedef __attribute__((ext_vector_type(4))) __bf16 bf16x4;
typedef __attribute__((ext_vector_type(4))) float f32x4;

#define MFMA16(a, b, c) __builtin_amdgcn_mfma_f32_16x16x32_bf16((a), (b), (c), 0, 0, 0)

// Problem dims
// B=32, T=1024, VOCAB=512, RANK=256
// x [32768, 512] f32 ; W_attn [512,768] ; b_attn[768] ; W_proj [256,512] ; b_proj[512]

// ---------------- weight convert+transpose (tiny) ----------------
__global__ __launch_bounds__(256) void cvt_wattn(const float* __restrict__ w,
                                                 bf16* __restrict__ wt) {
  int o = blockIdx.x * 256 + threadIdx.x;   // 768*512 = 393216
  int n = o >> 9, kk = o & 511;
  wt[o] = (bf16)w[kk * 768 + n];            // WT[n][k] = W[k][n]
}

__global__ __launch_bounds__(256) void cvt_wproj(const float* __restrict__ w,
                                                 bf16* __restrict__ wt) {
  int o = blockIdx.x * 256 + threadIdx.x;   // 512*256 = 131072
  int n = o >> 8, kk = o & 255;
  wt[o] = (bf16)w[kk * 512 + n];            // WT[n][k] = W[k][n]
}

// ---------------- qkv GEMM: [32768,512] x [512,768] ----------------
__global__ __launch_bounds__(256) void gemm_qkv(
    const float* __restrict__ x, const bf16* __restrict__ WT,
    const float* __restrict__ b_attn,
    bf16* __restrict__ qo, bf16* __restrict__ ko, bf16* __restrict__ vo) {
  __shared__ __attribute__((aligned(16))) bf16 As[128][40];
  __shared__ __attribute__((aligned(16))) bf16 Bs[128][40];
  const int tid = threadIdx.x;
  const int bn = blockIdx.x * 128;   // N fast (6) -> A-panel L2 reuse
  const int bm = blockIdx.y * 128;   // M (256)
  const int lane = tid & 63, wid = tid >> 6;
  const int l15 = lane & 15, lg = lane >> 4;
  const int wm = (wid >> 1) * 64, wn = (wid & 1) * 64;

  f32x4 acc[4][4] = {};

  const int srow = tid >> 1;
  const int scol = (tid & 1) * 16;
  const float* xp = x + (size_t)(bm + srow) * 512 + scol;
  const bf16* wp = WT + (size_t)(bn + srow) * 512 + scol;

  for (int kt = 0; kt < 16; ++kt) {
    f32x4 f0 = *(const f32x4*)(xp + kt * 32);
    f32x4 f1 = *(const f32x4*)(xp + kt * 32 + 4);
    f32x4 f2 = *(const f32x4*)(xp + kt * 32 + 8);
    f32x4 f3 = *(const f32x4*)(xp + kt * 32 + 12);
    bf16x8 h0, h1;
#pragma unroll
    for (int e = 0; e < 4; ++e) {
      h0[e] = (bf16)f0[e]; h0[e + 4] = (bf16)f1[e];
      h1[e] = (bf16)f2[e]; h1[e + 4] = (bf16)f3[e];
    }
    bf16x8 b0 = *(const bf16x8*)(wp + kt * 32);
    bf16x8 b1 = *(const bf16x8*)(wp + kt * 32 + 8);
    *(bf16x8*)&As[srow][scol] = h0;
    *(bf16x8*)&As[srow][scol + 8] = h1;
    *(bf16x8*)&Bs[srow][scol] = b0;
    *(bf16x8*)&Bs[srow][scol + 8] = b1;
    __syncthreads();
    bf16x8 af[4], bfr[4];
#pragma unroll
    for (int mi = 0; mi < 4; ++mi)
      af[mi] = *(const bf16x8*)&As[wm + mi * 16 + l15][lg * 8];
#pragma unroll
    for (int ni = 0; ni < 4; ++ni)
      bfr[ni] = *(const bf16x8*)&Bs[wn + ni * 16 + l15][lg * 8];
#pragma unroll
    for (int mi = 0; mi < 4; ++mi)
#pragma unroll
      for (int ni = 0; ni < 4; ++ni)
        acc[mi][ni] = MFMA16(af[mi], bfr[ni], acc[mi][ni]);
    __syncthreads();
  }

#pragma unroll
  for (int ni = 0; ni < 4; ++ni) {
    int gc = bn + wn + ni * 16 + l15;
    float bias = b_attn[gc];
    int seg = gc >> 8;         // 0=q 1=k 2=v  (frag never crosses a 256 boundary)
    int cc = gc & 255;
    bf16* op = (seg == 0) ? qo : ((seg == 1) ? ko : vo);
#pragma unroll
    for (int mi = 0; mi < 4; ++mi) {
      int gr = bm + wm + mi * 16 + lg * 4;
#pragma unroll
      for (int r = 0; r < 4; ++r) {
        float v = acc[mi][ni][r] + bias;
        op[(size_t)(gr + r) * 256 + cc] = (bf16)v;
      }
    }
  }
}

// ---------------- v -> v^T : [32][1024][256] -> [32][256][1024] ----------------
__global__ __launch_bounds__(256) void transpose_v(const bf16* __restrict__ v,
                                                   bf16* __restrict__ vt) {
  __shared__ bf16 tile[32][33];
  const int b = blockIdx.z;
  const int t0 = blockIdx.x * 32;
  const int d0 = blockIdx.y * 32;
  const int tid = threadIdx.x;
  const int r = tid >> 3, c4 = (tid & 7) * 4;
  bf16x4 in = *(const bf16x4*)(v + (size_t)(b * 1024 + t0 + r) * 256 + d0 + c4);
  tile[r][c4] = in[0]; tile[r][c4 + 1] = in[1];
  tile[r][c4 + 2] = in[2]; tile[r][c4 + 3] = in[3];
  __syncthreads();
  bf16x4 o;
  o[0] = tile[c4][r]; o[1] = tile[c4 + 1][r];
  o[2] = tile[c4 + 2][r]; o[3] = tile[c4 + 3][r];
  *(bf16x4*)(vt + (size_t)(b * 256 + d0 + r) * 1024 + t0 + c4) = o;
}

// ---------------- flash attention, causal, scale 1/16 ----------------
// v3: K-only in LDS with T14 async reg-staging; V^T fragments direct from
// global (L2-resident per batch via XCD swizzle); swapped QK^T so softmax
// rows are lane-local; defer-max rescale.
__global__ __launch_bounds__(256, 3) void attn_fwd(
    const bf16* __restrict__ q, const bf16* __restrict__ k,
    const bf16* __restrict__ vt, bf16* __restrict__ y) {
  __shared__ __attribute__((aligned(16))) bf16 Ks[64][264];   // [s][d], +8 pad
  __shared__ __attribute__((aligned(16))) bf16 Ps[4][16][72]; // per-wave P [q][s]
  const int tid = threadIdx.x, lane = tid & 63, wid = tid >> 6;
  const int l15 = lane & 15, lg = lane >> 4;

  // 1D grid of 512: id = xcd + 8*(qraw + 16*bg); batch = xcd + 8*bg
  // -> all 16 q-tiles of a batch land on one XCD (K/V/Vt L2-resident).
  const int id = blockIdx.x;
  const int xcd = id & 7;
  const int rest = id >> 3;
  const int qraw = rest & 15;
  const int bg = rest >> 4;
  const int b = xcd + 8 * bg;
  // heavy tiles first within each XCD stream, alternating heavy/light
  const int qt = (qraw & 1) ? (qraw >> 1) : (15 - (qraw >> 1));
  const int q0 = qt * 64 + wid * 16;

  bf16x8 qf[8];
  {
    const bf16* qp = q + (size_t)(b * 1024 + q0 + l15) * 256 + lg * 8;
#pragma unroll
    for (int d = 0; d < 8; ++d) qf[d] = *(const bf16x8*)(qp + d * 32);
  }
  f32x4 o[16] = {};
  float m_st = -1e30f;   // running max for q = q0 + l15 (replicated across lg)
  float l_st = 0.f;      // running denom for q = q0 + l15

  const bf16* kbase = k + (size_t)b * 1024 * 256;
  const bf16* vbase0 = vt + (size_t)b * 256 * 1024;
  const int srow0 = tid >> 5;          // staging row 0..7
  const int sc8 = (tid & 31) * 8;      // staging col (elements)

  // T14 prologue: issue K tile 0 loads into regs
  bf16x8 kreg[8];
#pragma unroll
  for (int i = 0; i < 8; ++i)
    kreg[i] = *(const bf16x8*)(kbase + (size_t)(srow0 + i * 8) * 256 + sc8);

  for (int tt = 0; tt <= qt; ++tt) {
    const int kv0 = tt * 64;
    __syncthreads();   // all waves done reading Ks (prev tile)
#pragma unroll
    for (int i = 0; i < 8; ++i)
      *(bf16x8*)&Ks[srow0 + i * 8][sc8] = kreg[i];
    __syncthreads();
    if (tt < qt) {     // issue next tile's loads; they drain under compute
      const bf16* kp = kbase + (size_t)((tt + 1) * 64 + srow0) * 256 + sc8;
#pragma unroll
      for (int i = 0; i < 8; ++i)
        kreg[i] = *(const bf16x8*)(kp + (size_t)i * 8 * 256);
    }

    // S^T = K Q^T : col = l15 = q, row = lg*4+r = s
    f32x4 st[4] = {};
    __builtin_amdgcn_s_setprio(1);
#pragma unroll
    for (int nf = 0; nf < 4; ++nf)
#pragma unroll
      for (int dc = 0; dc < 8; ++dc) {
        bf16x8 kb = *(const bf16x8*)&Ks[nf * 16 + l15][dc * 32 + lg * 8];
        st[nf] = MFMA16(kb, qf[dc], st[nf]);
      }
    __builtin_amdgcn_s_setprio(0);

    // scale + causal mask (in place); lane's 16 values belong to q = q0+l15
    const int qg = q0 + l15;
    float tmax = -1e30f;
#pragma unroll
    for (int nf = 0; nf < 4; ++nf)
#pragma unroll
      for (int r = 0; r < 4; ++r) {
        int sg = kv0 + nf * 16 + lg * 4 + r;
        float v = st[nf][r] * 0.0625f;
        v = (sg > qg) ? -1e30f : v;
        st[nf][r] = v;
        tmax = fmaxf(tmax, v);
      }
    tmax = fmaxf(tmax, __shfl_xor(tmax, 16, 64));
    tmax = fmaxf(tmax, __shfl_xor(tmax, 32, 64));

    // defer-max: only rescale when the tile max grew past THR=8
    if (!__all(tmax <= m_st + 8.f)) {
      float mnew = fmaxf(m_st, tmax);
      float corr = __expf(m_st - mnew);
      m_st = mnew;
      l_st *= corr;
      float corrT[4];
#pragma unroll
      for (int r = 0; r < 4; ++r) corrT[r] = __shfl(corr, lg * 4 + r, 64);
#pragma unroll
      for (int df = 0; df < 16; ++df)
#pragma unroll
        for (int r = 0; r < 4; ++r) o[df][r] *= corrT[r];
    }

    // P = exp(S - m), row sum, pack bf16, write P[q][s] to per-wave LDS
    float rsum = 0.f;
#pragma unroll
    for (int nf = 0; nf < 4; ++nf) {
      bf16x4 pk;
#pragma unroll
      for (int r = 0; r < 4; ++r) {
        float p = __expf(st[nf][r] - m_st);
        rsum += p;
        pk[r] = (bf16)p;
      }
      *(bf16x4*)&Ps[wid][l15][nf * 16 + lg * 4] = pk;
    }
    rsum += __shfl_xor(rsum, 16, 64);
    rsum += __shfl_xor(rsum, 32, 64);
    l_st += rsum;

    // PV: A = P rows (same-wave LDS), B = V^T rows DIRECT from global (L2)
    bf16x8 pa0 = *(const bf16x8*)&Ps[wid][l15][lg * 8];
    bf16x8 pa1 = *(const bf16x8*)&Ps[wid][l15][32 + lg * 8];
    const bf16* vp0 = vbase0 + (size_t)l15 * 1024 + kv0 + lg * 8;
    __builtin_amdgcn_s_setprio(1);
#pragma unroll
    for (int df = 0; df < 16; ++df) {
      const bf16* vp = vp0 + (size_t)df * 16 * 1024;
      bf16x8 vb0 = *(const bf16x8*)(vp);
      bf16x8 vb1 = *(const bf16x8*)(vp + 32);
      o[df] = MFMA16(pa0, vb0, o[df]);
      o[df] = MFMA16(pa1, vb1, o[df]);
    }
    __builtin_amdgcn_s_setprio(0);
  }

  // epilogue: divide by l (transpose stats from lane-q to row-q space)
  float lT[4];
#pragma unroll
  for (int r = 0; r < 4; ++r) lT[r] = __shfl(l_st, lg * 4 + r, 64);
  const size_t ybase = (size_t)(b * 1024 + q0 + lg * 4) * 256 + l15;
#pragma unroll
  for (int r = 0; r < 4; ++r) {
    float inv = 1.f / lT[r];
#pragma unroll
    for (int df = 0; df < 16; ++df)
      y[ybase + (size_t)r * 256 + df * 16] = (bf16)(o[df][r] * inv);
  }
}

// ---------------- proj GEMM + bias + exact GELU ----------------
__global__ __launch_bounds__(256) void gemm_proj(
    const bf16* __restrict__ y, const bf16* __restrict__ WT,
    const float* __restrict__ b_proj, float* __restrict__ out) {
  __shared__ __attribute__((aligned(16))) bf16 As[128][40];
  __shared__ __attribute__((aligned(16))) bf16 Bs[128][40];
  const int tid = threadIdx.x;
  const int bn = blockIdx.x * 128;  // N fast (4)
  const int bm = blockIdx.y * 128;  // M (256)
  const int lane = tid & 63, wid = tid >> 6;
  const int l15 = lane & 15, lg = lane >> 4;
  const int wm = (wid >> 1) * 64, wn = (wid & 1) * 64;
  f32x4 acc[4][4] = {};
  const int srow = tid >> 1, scol = (tid & 1) * 16;
  const bf16* yp = y + (size_t)(bm + srow) * 256 + scol;
  const bf16* wp = WT + (size_t)(bn + srow) * 256 + scol;
  for (int kt = 0; kt < 8; ++kt) {
    bf16x8 a0 = *(const bf16x8*)(yp + kt * 32);
    bf16x8 a1 = *(const bf16x8*)(yp + kt * 32 + 8);
    bf16x8 b0 = *(const bf16x8*)(wp + kt * 32);
    bf16x8 b1 = *(const bf16x8*)(wp + kt * 32 + 8);
    *(bf16x8*)&As[srow][scol] = a0;  *(bf16x8*)&As[srow][scol + 8] = a1;
    *(bf16x8*)&Bs[srow][scol] = b0;  *(bf16x8*)&Bs[srow][scol + 8] = b1;
    __syncthreads();
    bf16x8 af[4], bfr[4];
#pragma unroll
    for (int mi = 0; mi < 4; ++mi)
      af[mi] = *(const bf16x8*)&As[wm + mi * 16 + l15][lg * 8];
#pragma unroll
    for (int ni = 0; ni < 4; ++ni)
      bfr[ni] = *(const bf16x8*)&Bs[wn + ni * 16 + l15][lg * 8];
#pragma unroll
    for (int mi = 0; mi < 4; ++mi)
#pragma unroll
      for (int ni = 0; ni < 4; ++ni)
        acc[mi][ni] = MFMA16(af[mi], bfr[ni], acc[mi][ni]);
    __syncthreads();
  }
#pragma unroll
  for (int ni = 0; ni < 4; ++ni) {
    int gc = bn + wn + ni * 16 + l15;
    float bias = b_proj[gc];
#pragma unroll
    for (int mi = 0; mi < 4; ++mi) {
      int gr = bm + wm + mi * 16 + lg * 4;
#pragma unroll
      for (int r = 0; r < 4; ++r) {
        float v = acc[mi][ni][r] + bias;
        float g = 0.5f * v * (1.0f + erff(v * 0.70710678118654752f));
        out[(size_t)(gr + r) * 512 + gc] = g;
      }
    }
  }
}

extern "C" void kernel_launch(void* const* d_in, const int* in_sizes, int n_in,
                              void* d_out, int out_size, void* d_ws, size_t ws_size,
                              hipStream_t stream) {
  const float* x      = (const float*)d_in[0];
  const float* W_attn = (const float*)d_in[1];
  const float* b_attn = (const float*)d_in[2];
  const float* W_proj = (const float*)d_in[3];
  const float* b_proj = (const float*)d_in[4];
  float* out = (float*)d_out;
  char* ws = (char*)d_ws;

  const size_t SZ = 16777216;  // one [32,1024,256] bf16 buffer
  bf16* WT1 = (bf16*)(ws);                       // 768*512*2 = 786432
  bf16* WT2 = (bf16*)(ws + 786432);              // 512*256*2 = 262144
  bf16* qb  = (bf16*)(ws + 1048576);
  bf16* kb  = (bf16*)(ws + 1048576 + SZ);
  bf16* vb  = (bf16*)(ws + 1048576 + 2 * SZ);
  bf16* vtb = (bf16*)(ws + 1048576 + 3 * SZ);
  bf16* yb  = vb;  // v is dead after transpose_v; reuse its slot for y

  cvt_wattn<<<dim3(1536), dim3(256), 0, stream>>>(W_attn, WT1);
  cvt_wproj<<<dim3(512), dim3(256), 0, stream>>>(W_proj, WT2);
  gemm_qkv<<<dim3(6, 256), dim3(256), 0, stream>>>(x, WT1, b_attn, qb, kb, vb);
  transpose_v<<<dim3(32, 8, 32), dim3(256), 0, stream>>>(vb, vtb);
  attn_fwd<<<dim3(512), dim3(256), 0, stream>>>(qb, kb, vtb, yb);
  gemm_proj<<<dim3(4, 256), dim3(256), 0, stream>>>(yb, WT2, b_proj, out);
}

// Round 4
// 202.054 us; speedup vs baseline: 1.3226x; 1.3226x over previous
//
#include <hip/hip_runtime.h>
#include <hip/hip_bf16.h>
#include <math.h>

typedef __bf16 bf16;
typedef __attribute__((ext_vector_type(8))) __bf16 bf16x8;
typedef __attribute__((ext_vector_type(4))) __bf16 bf16x4;
typedef __attribute__((ext_vector_type(4))) float f32x4;

#define MFMA16(a, b, c) __builtin_amdgcn_mfma_f32_16x16x32_bf16((a), (b), (c), 0, 0, 0)

// Problem dims
// B=32, T=1024, VOCAB=512, RANK=256
// x [32768, 512] f32 ; W_attn [512,768] ; b_attn[768] ; W_proj [256,512] ; b_proj[512]

// ---------------- weight convert+transpose (tiny) ----------------
__global__ __launch_bounds__(256) void cvt_wattn(const float* __restrict__ w,
                                                 bf16* __restrict__ wt) {
  int o = blockIdx.x * 256 + threadIdx.x;   // 768*512 = 393216
  int n = o >> 9, kk = o & 511;
  wt[o] = (bf16)w[kk * 768 + n];            // WT[n][k] = W[k][n]
}

__global__ __launch_bounds__(256) void cvt_wproj(const float* __restrict__ w,
                                                 bf16* __restrict__ wt) {
  int o = blockIdx.x * 256 + threadIdx.x;   // 512*256 = 131072
  int n = o >> 8, kk = o & 255;
  wt[o] = (bf16)w[kk * 512 + n];            // WT[n][k] = W[k][n]
}

// ---------------- qkv GEMM: [32768,512] x [512,768] ----------------
__global__ __launch_bounds__(256) void gemm_qkv(
    const float* __restrict__ x, const bf16* __restrict__ WT,
    const float* __restrict__ b_attn,
    bf16* __restrict__ qo, bf16* __restrict__ ko, bf16* __restrict__ vo) {
  __shared__ __attribute__((aligned(16))) bf16 As[128][40];
  __shared__ __attribute__((aligned(16))) bf16 Bs[128][40];
  const int tid = threadIdx.x;
  const int bn = blockIdx.x * 128;   // N fast (6) -> A-panel L2 reuse
  const int bm = blockIdx.y * 128;   // M (256)
  const int lane = tid & 63, wid = tid >> 6;
  const int l15 = lane & 15, lg = lane >> 4;
  const int wm = (wid >> 1) * 64, wn = (wid & 1) * 64;

  f32x4 acc[4][4] = {};

  const int srow = tid >> 1;
  const int scol = (tid & 1) * 16;
  const float* xp = x + (size_t)(bm + srow) * 512 + scol;
  const bf16* wp = WT + (size_t)(bn + srow) * 512 + scol;

  for (int kt = 0; kt < 16; ++kt) {
    f32x4 f0 = *(const f32x4*)(xp + kt * 32);
    f32x4 f1 = *(const f32x4*)(xp + kt * 32 + 4);
    f32x4 f2 = *(const f32x4*)(xp + kt * 32 + 8);
    f32x4 f3 = *(const f32x4*)(xp + kt * 32 + 12);
    bf16x8 h0, h1;
#pragma unroll
    for (int e = 0; e < 4; ++e) {
      h0[e] = (bf16)f0[e]; h0[e + 4] = (bf16)f1[e];
      h1[e] = (bf16)f2[e]; h1[e + 4] = (bf16)f3[e];
    }
    bf16x8 b0 = *(const bf16x8*)(wp + kt * 32);
    bf16x8 b1 = *(const bf16x8*)(wp + kt * 32 + 8);
    *(bf16x8*)&As[srow][scol] = h0;
    *(bf16x8*)&As[srow][scol + 8] = h1;
    *(bf16x8*)&Bs[srow][scol] = b0;
    *(bf16x8*)&Bs[srow][scol + 8] = b1;
    __syncthreads();
    bf16x8 af[4], bfr[4];
#pragma unroll
    for (int mi = 0; mi < 4; ++mi)
      af[mi] = *(const bf16x8*)&As[wm + mi * 16 + l15][lg * 8];
#pragma unroll
    for (int ni = 0; ni < 4; ++ni)
      bfr[ni] = *(const bf16x8*)&Bs[wn + ni * 16 + l15][lg * 8];
#pragma unroll
    for (int mi = 0; mi < 4; ++mi)
#pragma unroll
      for (int ni = 0; ni < 4; ++ni)
        acc[mi][ni] = MFMA16(af[mi], bfr[ni], acc[mi][ni]);
    __syncthreads();
  }

#pragma unroll
  for (int ni = 0; ni < 4; ++ni) {
    int gc = bn + wn + ni * 16 + l15;
    float bias = b_attn[gc];
    int seg = gc >> 8;         // 0=q 1=k 2=v  (frag never crosses a 256 boundary)
    int cc = gc & 255;
    bf16* op = (seg == 0) ? qo : ((seg == 1) ? ko : vo);
#pragma unroll
    for (int mi = 0; mi < 4; ++mi) {
      int gr = bm + wm + mi * 16 + lg * 4;
#pragma unroll
      for (int r = 0; r < 4; ++r) {
        float v = acc[mi][ni][r] + bias;
        op[(size_t)(gr + r) * 256 + cc] = (bf16)v;
      }
    }
  }
}

// ---------------- v -> v^T : [32][1024][256] -> [32][256][1024] ----------------
__global__ __launch_bounds__(256) void transpose_v(const bf16* __restrict__ v,
                                                   bf16* __restrict__ vt) {
  __shared__ bf16 tile[32][33];
  const int b = blockIdx.z;
  const int t0 = blockIdx.x * 32;
  const int d0 = blockIdx.y * 32;
  const int tid = threadIdx.x;
  const int r = tid >> 3, c4 = (tid & 7) * 4;
  bf16x4 in = *(const bf16x4*)(v + (size_t)(b * 1024 + t0 + r) * 256 + d0 + c4);
  tile[r][c4] = in[0]; tile[r][c4 + 1] = in[1];
  tile[r][c4 + 2] = in[2]; tile[r][c4 + 3] = in[3];
  __syncthreads();
  bf16x4 o;
  o[0] = tile[c4][r]; o[1] = tile[c4 + 1][r];
  o[2] = tile[c4 + 2][r]; o[3] = tile[c4 + 3][r];
  *(bf16x4*)(vt + (size_t)(b * 256 + d0 + r) * 1024 + t0 + c4) = o;
}

// ---------------- flash attention, causal, scale 1/16 ----------------
// v4: K AND V^T in LDS (shared by 4 waves) + T14 async reg-staging for both
// (next tile's global loads issued right after stage-write, drain under
// compute) + XCD-swizzled grid (K/V L2-local) + swapped QK^T lane-local
// softmax + defer-max rescale.
__global__ __launch_bounds__(256) void attn_fwd(
    const bf16* __restrict__ q, const bf16* __restrict__ k,
    const bf16* __restrict__ vt, bf16* __restrict__ y) {
  __shared__ __attribute__((aligned(16))) bf16 Ks[64][264];   // [s][d], +8 pad
  __shared__ __attribute__((aligned(16))) bf16 Vt[256][72];   // [d][s], +8 pad
  __shared__ __attribute__((aligned(16))) bf16 Ps[4][16][72]; // per-wave P [q][s]
  const int tid = threadIdx.x, lane = tid & 63, wid = tid >> 6;
  const int l15 = lane & 15, lg = lane >> 4;

  // 1D grid of 512: id = xcd + 8*(qraw + 16*bg); batch = xcd + 8*bg
  // -> all 16 q-tiles of a batch land on one XCD (K/V/Vt L2-resident).
  const int id = blockIdx.x;
  const int xcd = id & 7;
  const int rest = id >> 3;
  const int qraw = rest & 15;
  const int bg = rest >> 4;
  const int b = xcd + 8 * bg;
  // heavy/light alternation within each XCD stream for tail balance
  const int qt = (qraw & 1) ? (qraw >> 1) : (15 - (qraw >> 1));
  const int q0 = qt * 64 + wid * 16;

  bf16x8 qf[8];
  {
    const bf16* qp = q + (size_t)(b * 1024 + q0 + l15) * 256 + lg * 8;
#pragma unroll
    for (int d = 0; d < 8; ++d) qf[d] = *(const bf16x8*)(qp + d * 32);
  }
  f32x4 o[16] = {};
  float m_st = -1e30f;   // running max for q = q0 + l15 (replicated across lg)
  float l_st = 0.f;      // running denom for q = q0 + l15

  const bf16* kbase = k + (size_t)b * 1024 * 256;
  const bf16* vtbase = vt + (size_t)b * 256 * 1024;
  // staging index maps (coalesced 16B per lane)
  const int ksr = tid >> 5, ksc = (tid & 31) * 8;   // K: 8 rows/iter of 512B
  const int vsr = tid >> 3, vsc = (tid & 7) * 8;    // Vt: 32 rows/iter of 128B

  // T14 prologue: issue tile-0 loads into regs
  bf16x8 kreg[8], vreg[8];
#pragma unroll
  for (int i = 0; i < 8; ++i)
    kreg[i] = *(const bf16x8*)(kbase + (size_t)(ksr + i * 8) * 256 + ksc);
#pragma unroll
  for (int i = 0; i < 8; ++i)
    vreg[i] = *(const bf16x8*)(vtbase + (size_t)(vsr + i * 32) * 1024 + vsc);

  for (int tt = 0; tt <= qt; ++tt) {
    const int kv0 = tt * 64;
    __syncthreads();   // all waves done reading Ks/Vt (previous tile)
#pragma unroll
    for (int i = 0; i < 8; ++i)
      *(bf16x8*)&Ks[ksr + i * 8][ksc] = kreg[i];
#pragma unroll
    for (int i = 0; i < 8; ++i)
      *(bf16x8*)&Vt[vsr + i * 32][vsc] = vreg[i];
    __syncthreads();
    if (tt < qt) {     // issue next tile's loads; drain under compute below
      const bf16* kp = kbase + (size_t)((tt + 1) * 64 + ksr) * 256 + ksc;
      const bf16* vp = vtbase + (size_t)vsr * 1024 + (tt + 1) * 64 + vsc;
#pragma unroll
      for (int i = 0; i < 8; ++i)
        kreg[i] = *(const bf16x8*)(kp + (size_t)i * 8 * 256);
#pragma unroll
      for (int i = 0; i < 8; ++i)
        vreg[i] = *(const bf16x8*)(vp + (size_t)i * 32 * 1024);
    }

    // S^T = K Q^T : col = l15 = q, row = lg*4+r = s
    f32x4 st[4] = {};
    __builtin_amdgcn_s_setprio(1);
#pragma unroll
    for (int nf = 0; nf < 4; ++nf)
#pragma unroll
      for (int dc = 0; dc < 8; ++dc) {
        bf16x8 kb = *(const bf16x8*)&Ks[nf * 16 + l15][dc * 32 + lg * 8];
        st[nf] = MFMA16(kb, qf[dc], st[nf]);
      }
    __builtin_amdgcn_s_setprio(0);

    // scale + causal mask (in place); lane's 16 values belong to q = q0+l15
    const int qg = q0 + l15;
    float tmax = -1e30f;
#pragma unroll
    for (int nf = 0; nf < 4; ++nf)
#pragma unroll
      for (int r = 0; r < 4; ++r) {
        int sg = kv0 + nf * 16 + lg * 4 + r;
        float v = st[nf][r] * 0.0625f;
        v = (sg > qg) ? -1e30f : v;
        st[nf][r] = v;
        tmax = fmaxf(tmax, v);
      }
    tmax = fmaxf(tmax, __shfl_xor(tmax, 16, 64));
    tmax = fmaxf(tmax, __shfl_xor(tmax, 32, 64));

    // defer-max: only rescale when the tile max grew past THR=8
    if (!__all(tmax <= m_st + 8.f)) {
      float mnew = fmaxf(m_st, tmax);
      float corr = __expf(m_st - mnew);
      m_st = mnew;
      l_st *= corr;
      float corrT[4];
#pragma unroll
      for (int r = 0; r < 4; ++r) corrT[r] = __shfl(corr, lg * 4 + r, 64);
#pragma unroll
      for (int df = 0; df < 16; ++df)
#pragma unroll
        for (int r = 0; r < 4; ++r) o[df][r] *= corrT[r];
    }

    // P = exp(S - m), row sum, pack bf16, write P[q][s] to per-wave LDS
    float rsum = 0.f;
#pragma unroll
    for (int nf = 0; nf < 4; ++nf) {
      bf16x4 pk;
#pragma unroll
      for (int r = 0; r < 4; ++r) {
        float p = __expf(st[nf][r] - m_st);
        rsum += p;
        pk[r] = (bf16)p;
      }
      *(bf16x4*)&Ps[wid][l15][nf * 16 + lg * 4] = pk;
    }
    rsum += __shfl_xor(rsum, 16, 64);
    rsum += __shfl_xor(rsum, 32, 64);
    l_st += rsum;

    // PV: A = P rows (same-wave LDS), B = V^T rows from LDS
    bf16x8 pa0 = *(const bf16x8*)&Ps[wid][l15][lg * 8];
    bf16x8 pa1 = *(const bf16x8*)&Ps[wid][l15][32 + lg * 8];
    __builtin_amdgcn_s_setprio(1);
#pragma unroll
    for (int df = 0; df < 16; ++df) {
      bf16x8 vb0 = *(const bf16x8*)&Vt[df * 16 + l15][lg * 8];
      bf16x8 vb1 = *(const bf16x8*)&Vt[df * 16 + l15][32 + lg * 8];
      o[df] = MFMA16(pa0, vb0, o[df]);
      o[df] = MFMA16(pa1, vb1, o[df]);
    }
    __builtin_amdgcn_s_setprio(0);
  }

  // epilogue: divide by l (transpose stats from lane-q to row-q space)
  float lT[4];
#pragma unroll
  for (int r = 0; r < 4; ++r) lT[r] = __shfl(l_st, lg * 4 + r, 64);
  const size_t ybase = (size_t)(b * 1024 + q0 + lg * 4) * 256 + l15;
#pragma unroll
  for (int r = 0; r < 4; ++r) {
    float inv = 1.f / lT[r];
#pragma unroll
    for (int df = 0; df < 16; ++df)
      y[ybase + (size_t)r * 256 + df * 16] = (bf16)(o[df][r] * inv);
  }
}

// ---------------- proj GEMM + bias + exact GELU ----------------
__global__ __launch_bounds__(256) void gemm_proj(
    const bf16* __restrict__ y, const bf16* __restrict__ WT,
    const float* __restrict__ b_proj, float* __restrict__ out) {
  __shared__ __attribute__((aligned(16))) bf16 As[128][40];
  __shared__ __attribute__((aligned(16))) bf16 Bs[128][40];
  const int tid = threadIdx.x;
  const int bn = blockIdx.x * 128;  // N fast (4)
  const int bm = blockIdx.y * 128;  // M (256)
  const int lane = tid & 63, wid = tid >> 6;
  const int l15 = lane & 15, lg = lane >> 4;
  const int wm = (wid >> 1) * 64, wn = (wid & 1) * 64;
  f32x4 acc[4][4] = {};
  const int srow = tid >> 1, scol = (tid & 1) * 16;
  const bf16* yp = y + (size_t)(bm + srow) * 256 + scol;
  const bf16* wp = WT + (size_t)(bn + srow) * 256 + scol;
  for (int kt = 0; kt < 8; ++kt) {
    bf16x8 a0 = *(const bf16x8*)(yp + kt * 32);
    bf16x8 a1 = *(const bf16x8*)(yp + kt * 32 + 8);
    bf16x8 b0 = *(const bf16x8*)(wp + kt * 32);
    bf16x8 b1 = *(const bf16x8*)(wp + kt * 32 + 8);
    *(bf16x8*)&As[srow][scol] = a0;  *(bf16x8*)&As[srow][scol + 8] = a1;
    *(bf16x8*)&Bs[srow][scol] = b0;  *(bf16x8*)&Bs[srow][scol + 8] = b1;
    __syncthreads();
    bf16x8 af[4], bfr[4];
#pragma unroll
    for (int mi = 0; mi < 4; ++mi)
      af[mi] = *(const bf16x8*)&As[wm + mi * 16 + l15][lg * 8];
#pragma unroll
    for (int ni = 0; ni < 4; ++ni)
      bfr[ni] = *(const bf16x8*)&Bs[wn + ni * 16 + l15][lg * 8];
#pragma unroll
    for (int mi = 0; mi < 4; ++mi)
#pragma unroll
      for (int ni = 0; ni < 4; ++ni)
        acc[mi][ni] = MFMA16(af[mi], bfr[ni], acc[mi][ni]);
    __syncthreads();
  }
#pragma unroll
  for (int ni = 0; ni < 4; ++ni) {
    int gc = bn + wn + ni * 16 + l15;
    float bias = b_proj[gc];
#pragma unroll
    for (int mi = 0; mi < 4; ++mi) {
      int gr = bm + wm + mi * 16 + lg * 4;
#pragma unroll
      for (int r = 0; r < 4; ++r) {
        float v = acc[mi][ni][r] + bias;
        float g = 0.5f * v * (1.0f + erff(v * 0.70710678118654752f));
        out[(size_t)(gr + r) * 512 + gc] = g;
      }
    }
  }
}

extern "C" void kernel_launch(void* const* d_in, const int* in_sizes, int n_in,
                              void* d_out, int out_size, void* d_ws, size_t ws_size,
                              hipStream_t stream) {
  const float* x      = (const float*)d_in[0];
  const float* W_attn = (const float*)d_in[1];
  const float* b_attn = (const float*)d_in[2];
  const float* W_proj = (const float*)d_in[3];
  const float* b_proj = (const float*)d_in[4];
  float* out = (float*)d_out;
  char* ws = (char*)d_ws;

  const size_t SZ = 16777216;  // one [32,1024,256] bf16 buffer
  bf16* WT1 = (bf16*)(ws);                       // 768*512*2 = 786432
  bf16* WT2 = (bf16*)(ws + 786432);              // 512*256*2 = 262144
  bf16* qb  = (bf16*)(ws + 1048576);
  bf16* kb  = (bf16*)(ws + 1048576 + SZ);
  bf16* vb  = (bf16*)(ws + 1048576 + 2 * SZ);
  bf16* vtb = (bf16*)(ws + 1048576 + 3 * SZ);
  bf16* yb  = vb;  // v is dead after transpose_v; reuse its slot for y

  cvt_wattn<<<dim3(1536), dim3(256), 0, stream>>>(W_attn, WT1);
  cvt_wproj<<<dim3(512), dim3(256), 0, stream>>>(W_proj, WT2);
  gemm_qkv<<<dim3(6, 256), dim3(256), 0, stream>>>(x, WT1, b_attn, qb, kb, vb);
  transpose_v<<<dim3(32, 8, 32), dim3(256), 0, stream>>>(vb, vtb);
  attn_fwd<<<dim3(512), dim3(256), 0, stream>>>(qb, kb, vtb, yb);
  gemm_proj<<<dim3(4, 256), dim3(256), 0, stream>>>(yb, WT2, b_proj, out);
}

// Round 5
// 152.482 us; speedup vs baseline: 1.7526x; 1.3251x over previous
//
#include <hip/hip_runtime.h>
#include <hip/hip_bf16.h>
#include <math.h>

typedef __bf16 bf16;
typedef __attribute__((ext_vector_type(8))) __bf16 bf16x8;
typedef __attribute__((ext_vector_type(4))) __bf16 bf16x4;
typedef __attribute__((ext_vector_type(4))) float f32x4;

#define MFMA16(a, b, c) __builtin_amdgcn_mfma_f32_16x16x32_bf16((a), (b), (c), 0, 0, 0)

// Problem dims
// B=32, T=1024, VOCAB=512, RANK=256
// x [32768, 512] f32 ; W_attn [512,768] ; b_attn[768] ; W_proj [256,512] ; b_proj[512]

// ---------------- weight convert+transpose (tiny) ----------------
__global__ __launch_bounds__(256) void cvt_wattn(const float* __restrict__ w,
                                                 bf16* __restrict__ wt) {
  int o = blockIdx.x * 256 + threadIdx.x;   // 768*512 = 393216
  int n = o >> 9, kk = o & 511;
  wt[o] = (bf16)w[kk * 768 + n];            // WT[n][k] = W[k][n]
}

__global__ __launch_bounds__(256) void cvt_wproj(const float* __restrict__ w,
                                                 bf16* __restrict__ wt) {
  int o = blockIdx.x * 256 + threadIdx.x;   // 512*256 = 131072
  int n = o >> 8, kk = o & 255;
  wt[o] = (bf16)w[kk * 512 + n];            // WT[n][k] = W[k][n]
}

// ---------------- qkv GEMM: [32768,512] x [512,768] ----------------
// v5: XCD-chunked linear grid (all 6 N-blocks of an M-panel consecutive on
// one XCD -> A-panel fetched ~once from HBM) + T14 reg-prefetch of next
// K-step (f32->bf16 conversion done at load time, off the barrier path).
__global__ __launch_bounds__(256) void gemm_qkv(
    const float* __restrict__ x, const bf16* __restrict__ WT,
    const float* __restrict__ b_attn,
    bf16* __restrict__ qo, bf16* __restrict__ ko, bf16* __restrict__ vo) {
  __shared__ __attribute__((aligned(16))) bf16 As[128][40];
  __shared__ __attribute__((aligned(16))) bf16 Bs[128][40];
  const int tid = threadIdx.x;
  // 1536 blocks: xcd = id&7 owns 192 blocks = 32 M-panels x 6 N-blocks,
  // N fastest within the per-XCD stream -> A-panel L2-local.
  const int id = blockIdx.x;
  const int xcd = id & 7;
  const int rest = id >> 3;          // 0..191
  const int bmL = rest / 6;          // 0..31
  const int bn = (rest % 6) * 128;
  const int bm = (xcd * 32 + bmL) * 128;
  const int lane = tid & 63, wid = tid >> 6;
  const int l15 = lane & 15, lg = lane >> 4;
  const int wm = (wid >> 1) * 64, wn = (wid & 1) * 64;

  f32x4 acc[4][4] = {};

  const int srow = tid >> 1;
  const int scol = (tid & 1) * 16;
  const float* xp = x + (size_t)(bm + srow) * 512 + scol;
  const bf16* wp = WT + (size_t)(bn + srow) * 512 + scol;

  // T14 prologue: load + convert K-step 0 into regs
  bf16x8 ha[2], hb[2];
  {
    f32x4 f0 = *(const f32x4*)(xp);
    f32x4 f1 = *(const f32x4*)(xp + 4);
    f32x4 f2 = *(const f32x4*)(xp + 8);
    f32x4 f3 = *(const f32x4*)(xp + 12);
#pragma unroll
    for (int e = 0; e < 4; ++e) {
      ha[0][e] = (bf16)f0[e]; ha[0][e + 4] = (bf16)f1[e];
      ha[1][e] = (bf16)f2[e]; ha[1][e + 4] = (bf16)f3[e];
    }
    hb[0] = *(const bf16x8*)(wp);
    hb[1] = *(const bf16x8*)(wp + 8);
  }

  for (int kt = 0; kt < 16; ++kt) {
    __syncthreads();   // previous tile's LDS reads done
    *(bf16x8*)&As[srow][scol] = ha[0];
    *(bf16x8*)&As[srow][scol + 8] = ha[1];
    *(bf16x8*)&Bs[srow][scol] = hb[0];
    *(bf16x8*)&Bs[srow][scol + 8] = hb[1];
    __syncthreads();
    if (kt < 15) {     // prefetch next K-step; drains under the MFMAs below
      f32x4 f0 = *(const f32x4*)(xp + (kt + 1) * 32);
      f32x4 f1 = *(const f32x4*)(xp + (kt + 1) * 32 + 4);
      f32x4 f2 = *(const f32x4*)(xp + (kt + 1) * 32 + 8);
      f32x4 f3 = *(const f32x4*)(xp + (kt + 1) * 32 + 12);
#pragma unroll
      for (int e = 0; e < 4; ++e) {
        ha[0][e] = (bf16)f0[e]; ha[0][e + 4] = (bf16)f1[e];
        ha[1][e] = (bf16)f2[e]; ha[1][e + 4] = (bf16)f3[e];
      }
      hb[0] = *(const bf16x8*)(wp + (kt + 1) * 32);
      hb[1] = *(const bf16x8*)(wp + (kt + 1) * 32 + 8);
    }
    bf16x8 af[4], bfr[4];
#pragma unroll
    for (int mi = 0; mi < 4; ++mi)
      af[mi] = *(const bf16x8*)&As[wm + mi * 16 + l15][lg * 8];
#pragma unroll
    for (int ni = 0; ni < 4; ++ni)
      bfr[ni] = *(const bf16x8*)&Bs[wn + ni * 16 + l15][lg * 8];
    __builtin_amdgcn_s_setprio(1);
#pragma unroll
    for (int mi = 0; mi < 4; ++mi)
#pragma unroll
      for (int ni = 0; ni < 4; ++ni)
        acc[mi][ni] = MFMA16(af[mi], bfr[ni], acc[mi][ni]);
    __builtin_amdgcn_s_setprio(0);
  }

#pragma unroll
  for (int ni = 0; ni < 4; ++ni) {
    int gc = bn + wn + ni * 16 + l15;
    float bias = b_attn[gc];
    int seg = gc >> 8;         // 0=q 1=k 2=v  (frag never crosses a 256 boundary)
    int cc = gc & 255;
    bf16* op = (seg == 0) ? qo : ((seg == 1) ? ko : vo);
#pragma unroll
    for (int mi = 0; mi < 4; ++mi) {
      int gr = bm + wm + mi * 16 + lg * 4;
#pragma unroll
      for (int r = 0; r < 4; ++r) {
        float v = acc[mi][ni][r] + bias;
        op[(size_t)(gr + r) * 256 + cc] = (bf16)v;
      }
    }
  }
}

// ---------------- v -> v^T : [32][1024][256] -> [32][256][1024] ----------------
__global__ __launch_bounds__(256) void transpose_v(const bf16* __restrict__ v,
                                                   bf16* __restrict__ vt) {
  __shared__ bf16 tile[32][33];
  const int b = blockIdx.z;
  const int t0 = blockIdx.x * 32;
  const int d0 = blockIdx.y * 32;
  const int tid = threadIdx.x;
  const int r = tid >> 3, c4 = (tid & 7) * 4;
  bf16x4 in = *(const bf16x4*)(v + (size_t)(b * 1024 + t0 + r) * 256 + d0 + c4);
  tile[r][c4] = in[0]; tile[r][c4 + 1] = in[1];
  tile[r][c4 + 2] = in[2]; tile[r][c4 + 3] = in[3];
  __syncthreads();
  bf16x4 o;
  o[0] = tile[c4][r]; o[1] = tile[c4 + 1][r];
  o[2] = tile[c4 + 2][r]; o[3] = tile[c4 + 3][r];
  *(bf16x4*)(vt + (size_t)(b * 256 + d0 + r) * 1024 + t0 + c4) = o;
}

// ---------------- flash attention, causal, scale 1/16 ----------------
// v5: QBLK=128 (8 waves, 512 threads) -> 256 blocks = 1/CU, all resident;
// halves the serial tile-step count on the critical CU and removes the
// heavy/heavy pairing hazard. K + V^T in LDS, T14 async reg-staging,
// XCD-grouped batches, swapped QK^T lane-local softmax, defer-max.
__global__ __launch_bounds__(512) void attn_fwd(
    const bf16* __restrict__ q, const bf16* __restrict__ k,
    const bf16* __restrict__ vt, bf16* __restrict__ y) {
  __shared__ __attribute__((aligned(16))) bf16 Ks[64][264];   // [s][d], +8 pad
  __shared__ __attribute__((aligned(16))) bf16 Vt[256][72];   // [d][s], +8 pad
  __shared__ __attribute__((aligned(16))) bf16 Ps[8][16][72]; // per-wave P [q][s]
  const int tid = threadIdx.x, lane = tid & 63, wid = tid >> 6;
  const int l15 = lane & 15, lg = lane >> 4;

  // 256 blocks: id = xcd + 8*(qidx + 8*bg); batch = xcd + 8*bg
  // -> each XCD handles 4 batches; K/V^T L2-resident per XCD.
  const int id = blockIdx.x;
  const int xcd = id & 7;
  const int rest = id >> 3;
  const int qt = rest & 7;         // q-tile of 128 rows
  const int bg = rest >> 3;
  const int b = xcd + 8 * bg;
  const int q0 = qt * 128 + wid * 16;

  bf16x8 qf[8];
  {
    const bf16* qp = q + (size_t)(b * 1024 + q0 + l15) * 256 + lg * 8;
#pragma unroll
    for (int d = 0; d < 8; ++d) qf[d] = *(const bf16x8*)(qp + d * 32);
  }
  f32x4 o[16] = {};
  float m_st = -1e30f;   // running max for q = q0 + l15 (replicated across lg)
  float l_st = 0.f;      // running denom

  const bf16* kbase = k + (size_t)b * 1024 * 256;
  const bf16* vtbase = vt + (size_t)b * 256 * 1024;
  // staging maps (512 threads, 16B per thread per chunk)
  const int ksr = tid >> 5, ksc = (tid & 31) * 8;   // K: 16 rows per iter
  const int vsr = tid >> 3, vsc = (tid & 7) * 8;    // Vt: 64 rows per iter

  const int ntiles = 2 * qt + 2;

  // T14 prologue: issue tile-0 loads into regs
  bf16x8 kreg[4], vreg[4];
#pragma unroll
  for (int i = 0; i < 4; ++i)
    kreg[i] = *(const bf16x8*)(kbase + (size_t)(ksr + i * 16) * 256 + ksc);
#pragma unroll
  for (int i = 0; i < 4; ++i)
    vreg[i] = *(const bf16x8*)(vtbase + (size_t)(vsr + i * 64) * 1024 + vsc);

  for (int tt = 0; tt < ntiles; ++tt) {
    const int kv0 = tt * 64;
    __syncthreads();   // all waves done reading Ks/Vt (previous tile)
#pragma unroll
    for (int i = 0; i < 4; ++i)
      *(bf16x8*)&Ks[ksr + i * 16][ksc] = kreg[i];
#pragma unroll
    for (int i = 0; i < 4; ++i)
      *(bf16x8*)&Vt[vsr + i * 64][vsc] = vreg[i];
    __syncthreads();
    if (tt + 1 < ntiles) {   // next tile's loads drain under compute below
      const bf16* kp = kbase + (size_t)(kv0 + 64 + ksr) * 256 + ksc;
      const bf16* vp = vtbase + (size_t)vsr * 1024 + kv0 + 64 + vsc;
#pragma unroll
      for (int i = 0; i < 4; ++i)
        kreg[i] = *(const bf16x8*)(kp + (size_t)i * 16 * 256);
#pragma unroll
      for (int i = 0; i < 4; ++i)
        vreg[i] = *(const bf16x8*)(vp + (size_t)i * 64 * 1024);
    }

    // S^T = K Q^T : col = l15 = q, row = lg*4+r = s
    f32x4 st[4] = {};
    __builtin_amdgcn_s_setprio(1);
#pragma unroll
    for (int nf = 0; nf < 4; ++nf)
#pragma unroll
      for (int dc = 0; dc < 8; ++dc) {
        bf16x8 kb = *(const bf16x8*)&Ks[nf * 16 + l15][dc * 32 + lg * 8];
        st[nf] = MFMA16(kb, qf[dc], st[nf]);
      }
    __builtin_amdgcn_s_setprio(0);

    // scale + causal mask (in place); lane's 16 values belong to q = q0+l15
    const int qg = q0 + l15;
    float tmax = -1e30f;
#pragma unroll
    for (int nf = 0; nf < 4; ++nf)
#pragma unroll
      for (int r = 0; r < 4; ++r) {
        int sg = kv0 + nf * 16 + lg * 4 + r;
        float v = st[nf][r] * 0.0625f;
        v = (sg > qg) ? -1e30f : v;
        st[nf][r] = v;
        tmax = fmaxf(tmax, v);
      }
    tmax = fmaxf(tmax, __shfl_xor(tmax, 16, 64));
    tmax = fmaxf(tmax, __shfl_xor(tmax, 32, 64));

    // defer-max: only rescale when the tile max grew past THR=8
    if (!__all(tmax <= m_st + 8.f)) {
      float mnew = fmaxf(m_st, tmax);
      float corr = __expf(m_st - mnew);
      m_st = mnew;
      l_st *= corr;
      float corrT[4];
#pragma unroll
      for (int r = 0; r < 4; ++r) corrT[r] = __shfl(corr, lg * 4 + r, 64);
#pragma unroll
      for (int df = 0; df < 16; ++df)
#pragma unroll
        for (int r = 0; r < 4; ++r) o[df][r] *= corrT[r];
    }

    // P = exp(S - m), row sum, pack bf16, write P[q][s] to per-wave LDS
    float rsum = 0.f;
#pragma unroll
    for (int nf = 0; nf < 4; ++nf) {
      bf16x4 pk;
#pragma unroll
      for (int r = 0; r < 4; ++r) {
        float p = __expf(st[nf][r] - m_st);
        rsum += p;
        pk[r] = (bf16)p;
      }
      *(bf16x4*)&Ps[wid][l15][nf * 16 + lg * 4] = pk;
    }
    rsum += __shfl_xor(rsum, 16, 64);
    rsum += __shfl_xor(rsum, 32, 64);
    l_st += rsum;

    // PV: A = P rows (same-wave LDS), B = V^T rows from LDS
    bf16x8 pa0 = *(const bf16x8*)&Ps[wid][l15][lg * 8];
    bf16x8 pa1 = *(const bf16x8*)&Ps[wid][l15][32 + lg * 8];
    __builtin_amdgcn_s_setprio(1);
#pragma unroll
    for (int df = 0; df < 16; ++df) {
      bf16x8 vb0 = *(const bf16x8*)&Vt[df * 16 + l15][lg * 8];
      bf16x8 vb1 = *(const bf16x8*)&Vt[df * 16 + l15][32 + lg * 8];
      o[df] = MFMA16(pa0, vb0, o[df]);
      o[df] = MFMA16(pa1, vb1, o[df]);
    }
    __builtin_amdgcn_s_setprio(0);
  }

  // epilogue: divide by l (transpose stats from lane-q to row-q space)
  float lT[4];
#pragma unroll
  for (int r = 0; r < 4; ++r) lT[r] = __shfl(l_st, lg * 4 + r, 64);
  const size_t ybase = (size_t)(b * 1024 + q0 + lg * 4) * 256 + l15;
#pragma unroll
  for (int r = 0; r < 4; ++r) {
    float inv = 1.f / lT[r];
#pragma unroll
    for (int df = 0; df < 16; ++df)
      y[ybase + (size_t)r * 256 + df * 16] = (bf16)(o[df][r] * inv);
  }
}

// ---------------- proj GEMM + bias + exact GELU ----------------
__global__ __launch_bounds__(256) void gemm_proj(
    const bf16* __restrict__ y, const bf16* __restrict__ WT,
    const float* __restrict__ b_proj, float* __restrict__ out) {
  __shared__ __attribute__((aligned(16))) bf16 As[128][40];
  __shared__ __attribute__((aligned(16))) bf16 Bs[128][40];
  const int tid = threadIdx.x;
  const int bn = blockIdx.x * 128;  // N fast (4)
  const int bm = blockIdx.y * 128;  // M (256)
  const int lane = tid & 63, wid = tid >> 6;
  const int l15 = lane & 15, lg = lane >> 4;
  const int wm = (wid >> 1) * 64, wn = (wid & 1) * 64;
  f32x4 acc[4][4] = {};
  const int srow = tid >> 1, scol = (tid & 1) * 16;
  const bf16* yp = y + (size_t)(bm + srow) * 256 + scol;
  const bf16* wp = WT + (size_t)(bn + srow) * 256 + scol;
  for (int kt = 0; kt < 8; ++kt) {
    bf16x8 a0 = *(const bf16x8*)(yp + kt * 32);
    bf16x8 a1 = *(const bf16x8*)(yp + kt * 32 + 8);
    bf16x8 b0 = *(const bf16x8*)(wp + kt * 32);
    bf16x8 b1 = *(const bf16x8*)(wp + kt * 32 + 8);
    *(bf16x8*)&As[srow][scol] = a0;  *(bf16x8*)&As[srow][scol + 8] = a1;
    *(bf16x8*)&Bs[srow][scol] = b0;  *(bf16x8*)&Bs[srow][scol + 8] = b1;
    __syncthreads();
    bf16x8 af[4], bfr[4];
#pragma unroll
    for (int mi = 0; mi < 4; ++mi)
      af[mi] = *(const bf16x8*)&As[wm + mi * 16 + l15][lg * 8];
#pragma unroll
    for (int ni = 0; ni < 4; ++ni)
      bfr[ni] = *(const bf16x8*)&Bs[wn + ni * 16 + l15][lg * 8];
#pragma unroll
    for (int mi = 0; mi < 4; ++mi)
#pragma unroll
      for (int ni = 0; ni < 4; ++ni)
        acc[mi][ni] = MFMA16(af[mi], bfr[ni], acc[mi][ni]);
    __syncthreads();
  }
#pragma unroll
  for (int ni = 0; ni < 4; ++ni) {
    int gc = bn + wn + ni * 16 + l15;
    float bias = b_proj[gc];
#pragma unroll
    for (int mi = 0; mi < 4; ++mi) {
      int gr = bm + wm + mi * 16 + lg * 4;
#pragma unroll
      for (int r = 0; r < 4; ++r) {
        float v = acc[mi][ni][r] + bias;
        float g = 0.5f * v * (1.0f + erff(v * 0.70710678118654752f));
        out[(size_t)(gr + r) * 512 + gc] = g;
      }
    }
  }
}

extern "C" void kernel_launch(void* const* d_in, const int* in_sizes, int n_in,
                              void* d_out, int out_size, void* d_ws, size_t ws_size,
                              hipStream_t stream) {
  const float* x      = (const float*)d_in[0];
  const float* W_attn = (const float*)d_in[1];
  const float* b_attn = (const float*)d_in[2];
  const float* W_proj = (const float*)d_in[3];
  const float* b_proj = (const float*)d_in[4];
  float* out = (float*)d_out;
  char* ws = (char*)d_ws;

  const size_t SZ = 16777216;  // one [32,1024,256] bf16 buffer
  bf16* WT1 = (bf16*)(ws);                       // 768*512*2 = 786432
  bf16* WT2 = (bf16*)(ws + 786432);              // 512*256*2 = 262144
  bf16* qb  = (bf16*)(ws + 1048576);
  bf16* kb  = (bf16*)(ws + 1048576 + SZ);
  bf16* vb  = (bf16*)(ws + 1048576 + 2 * SZ);
  bf16* vtb = (bf16*)(ws + 1048576 + 3 * SZ);
  bf16* yb  = vb;  // v is dead after transpose_v; reuse its slot for y

  cvt_wattn<<<dim3(1536), dim3(256), 0, stream>>>(W_attn, WT1);
  cvt_wproj<<<dim3(512), dim3(256), 0, stream>>>(W_proj, WT2);
  gemm_qkv<<<dim3(1536), dim3(256), 0, stream>>>(x, WT1, b_attn, qb, kb, vb);
  transpose_v<<<dim3(32, 8, 32), dim3(256), 0, stream>>>(vb, vtb);
  attn_fwd<<<dim3(256), dim3(512), 0, stream>>>(qb, kb, vtb, yb);
  gemm_proj<<<dim3(4, 256), dim3(256), 0, stream>>>(yb, WT2, b_proj, out);
}